// Round 3
// baseline (348.927 us; speedup 1.0000x reference)
//
#include <hip/hip_runtime.h>
#include <cstdint>

#define N_FACES_C 40000
#define N_EDGES_C 60000
#define CH        512

typedef __bf16 bf16_t;
typedef __bf16 bf16x8 __attribute__((ext_vector_type(8)));
typedef float  f32x4  __attribute__((ext_vector_type(4)));
static_assert(sizeof(bf16x8) == 16, "bf16x8 must be 16B");

// ---------------- runtime input-dtype detection ----------------
// vals is all-ones: first u32 word = 0x3F803F80 if bf16-packed, 0x3F800000 if f32.
__global__ void detect_dtype(const unsigned int* __restrict__ vals_bits, int* __restrict__ flag) {
  if (blockIdx.x == 0 && threadIdx.x == 0)
    *flag = (vals_bits[0] == 0x3F803F80u) ? 1 : 0;  // 1 = inputs are bf16
}

__device__ __forceinline__ float load_val(const void* vals, int i, bool isbf16) {
  return isbf16 ? (float)((const bf16_t*)vals)[i] : ((const float*)vals)[i];
}

// ---------------- degree + count (atomic histogram) ----------------
__global__ void count_deg_kernel(const int* __restrict__ ei, const int* __restrict__ fi,
                                 const void* __restrict__ vals, int nnz,
                                 float* __restrict__ deg_e, float* __restrict__ deg_f,
                                 int* __restrict__ cnt_e, int* __restrict__ cnt_f,
                                 const int* __restrict__ flag) {
  int i = blockIdx.x * 256 + threadIdx.x;
  if (i >= nnz) return;
  bool isb = (*flag != 0);
  float v = load_val(vals, i, isb);
  int e = ei[i], f = fi[i];
  atomicAdd(&deg_e[e], v);
  atomicAdd(&deg_f[f], v);
  atomicAdd(&cnt_e[e], 1);
  atomicAdd(&cnt_f[f], 1);
}

// ---------------- 3-phase exclusive scan (chunk = 1024/block) ----------------
__global__ void scan_part(const int* __restrict__ cnt, int n, int* __restrict__ bsum) {
  __shared__ int wsum[4];
  int b = blockIdx.x, t = threadIdx.x;
  int lane = t & 63, wave = t >> 6;
  int base = b * 1024 + t * 4;
  int s = 0;
#pragma unroll
  for (int k = 0; k < 4; ++k) {
    int idx = base + k;
    if (idx < n) s += cnt[idx];
  }
#pragma unroll
  for (int o = 32; o > 0; o >>= 1) s += __shfl_down(s, o);
  if (lane == 0) wsum[wave] = s;
  __syncthreads();
  if (t == 0) bsum[b] = wsum[0] + wsum[1] + wsum[2] + wsum[3];
}

__global__ void scan_bsums(int* bsum, int nb) {
  int lane = threadIdx.x;  // 64 threads, nb <= 64
  int orig = (lane < nb) ? bsum[lane] : 0;
  int v = orig;
#pragma unroll
  for (int o = 1; o < 64; o <<= 1) {
    int u = __shfl_up(v, o);
    if (lane >= o) v += u;
  }
  if (lane < nb) bsum[lane] = v - orig;  // exclusive
}

__global__ void scan_final(const int* __restrict__ cnt, int n, const int* __restrict__ bsum,
                           int* __restrict__ ptr, int* __restrict__ cur) {
  __shared__ int wsum[4];
  int b = blockIdx.x, t = threadIdx.x;
  int lane = t & 63, wave = t >> 6;
  int base = b * 1024 + t * 4;
  int c[4];
  int s = 0;
#pragma unroll
  for (int k = 0; k < 4; ++k) {
    int idx = base + k;
    c[k] = (idx < n) ? cnt[idx] : 0;
    s += c[k];
  }
  int v = s;
#pragma unroll
  for (int o = 1; o < 64; o <<= 1) {
    int u = __shfl_up(v, o);
    if (lane >= o) v += u;
  }
  if (lane == 63) wsum[wave] = v;
  __syncthreads();
  int woff = 0;
  for (int w = 0; w < wave; ++w) woff += wsum[w];
  int run = bsum[b] + woff + (v - s);
#pragma unroll
  for (int k = 0; k < 4; ++k) {
    int idx = base + k;
    if (idx < n) {
      ptr[idx] = run;
      cur[idx] = run;
      run += c[k];
      if (idx == n - 1) ptr[n] = run;
    }
  }
}

// ---------------- CSR fill (both directions in one pass) ----------------
__global__ void csr_fill(const int* __restrict__ ei, const int* __restrict__ fi,
                         const void* __restrict__ vals, int nnz,
                         int* __restrict__ cur_e, int* __restrict__ col_e, float* __restrict__ val_e,
                         int* __restrict__ cur_f, int* __restrict__ col_f, float* __restrict__ val_f,
                         const int* __restrict__ flag) {
  int i = blockIdx.x * 256 + threadIdx.x;
  if (i >= nnz) return;
  bool isb = (*flag != 0);
  int e = ei[i], f = fi[i];
  float v = load_val(vals, i, isb);
  int p = atomicAdd(&cur_e[e], 1);
  col_e[p] = f; val_e[p] = v;
  int q = atomicAdd(&cur_f[f], 1);
  col_f[q] = e; val_f[q] = v;
}

// ---------------- 512x512 transpose (W -> W^T, bf16 out, dtype-flag in) ----------------
__global__ void transposeW(const void* __restrict__ W, bf16_t* __restrict__ Wt,
                           const int* __restrict__ flag) {
  __shared__ bf16_t tile[32][33];
  bool isb = (*flag != 0);
  int bx = blockIdx.x * 32, by = blockIdx.y * 32;
  int tx = threadIdx.x, ty = threadIdx.y;  // (32, 8)
#pragma unroll
  for (int r = 0; r < 32; r += 8) {
    size_t idx = (size_t)(by + ty + r) * CH + bx + tx;
    tile[ty + r][tx] = isb ? ((const bf16_t*)W)[idx] : (bf16_t)((const float*)W)[idx];
  }
  __syncthreads();
#pragma unroll
  for (int r = 0; r < 32; r += 8)
    Wt[(size_t)(bx + ty + r) * CH + by + tx] = tile[tx][ty + r];
}

// ---------------- CSR-gather SpMM + deg-divide (one wave per row), bf16 out ----------------
// X dtype: bf16 if (force_bf16 || *flag), else f32.
__global__ void spmm_div(const int* __restrict__ ptr, const int* __restrict__ cols,
                         const float* __restrict__ vals, const void* __restrict__ X,
                         const float* __restrict__ deg, bf16_t* __restrict__ Y,
                         int nRows, int nCols, int nnz,
                         const int* __restrict__ flag, int force_bf16) {
  int row = blockIdx.x * 4 + (threadIdx.x >> 6);
  if (row >= nRows) return;
  bool xb = force_bf16 || (*flag != 0);
  int lane = threadIdx.x & 63;
  int beg = ptr[row], end = ptr[row + 1];
  if (beg < 0) beg = 0;
  if (end > nnz) end = nnz;
  float acc[8];
#pragma unroll
  for (int t = 0; t < 8; ++t) acc[t] = 0.f;
  const int lofs = lane * 8;
  if (xb) {
    const bf16_t* Xb = (const bf16_t*)X;
    for (int p = beg; p < end; ++p) {
      int c = cols[p];
      if ((unsigned)c >= (unsigned)nCols) c = 0;  // insurance vs wild index
      float v = vals[p];
      bf16x8 xv = *(const bf16x8*)(Xb + (size_t)c * CH + lofs);
#pragma unroll
      for (int t = 0; t < 8; ++t) acc[t] += v * (float)xv[t];
    }
  } else {
    const float* Xf = (const float*)X;
    for (int p = beg; p < end; ++p) {
      int c = cols[p];
      if ((unsigned)c >= (unsigned)nCols) c = 0;
      float v = vals[p];
      const float* src = Xf + (size_t)c * CH + lofs;
      float4 a = *(const float4*)src;
      float4 b = *(const float4*)(src + 4);
      acc[0] += v * a.x; acc[1] += v * a.y; acc[2] += v * a.z; acc[3] += v * a.w;
      acc[4] += v * b.x; acc[5] += v * b.y; acc[6] += v * b.z; acc[7] += v * b.w;
    }
  }
  float d = deg[row];
  float invd = (d != 0.f) ? (1.0f / d) : 0.f;
  bf16x8 o;
#pragma unroll
  for (int t = 0; t < 8; ++t) o[t] = (bf16_t)(acc[t] * invd);
  *(bf16x8*)(Y + (size_t)row * CH + lofs) = o;
}

// ---------------- bf16 GEMM + sigmoid epilogue: C = sigmoid(A[M,K] * B), Bt = B^T ----------------
// Output: bf16 unless (final_out && *flag==0) -> f32.
__global__ __launch_bounds__(256)
void gemm_sig(const bf16_t* __restrict__ A, const bf16_t* __restrict__ Bt,
              void* __restrict__ C, int M, int N, int K,
              const int* __restrict__ flag, int final_out) {
  __shared__ __align__(16) bf16_t As[128 * 32];  // [row][k], contiguous k
  __shared__ __align__(16) bf16_t Bs[128 * 32];  // [n][k], contiguous k
  const int tid  = threadIdx.x;
  const int lane = tid & 63;
  const int wave = tid >> 6;
  const int r0 = blockIdx.x * 128;
  const int c0 = blockIdx.y * 128;
  const int wr = (wave >> 1) * 64;
  const int wc = (wave & 1) * 64;
  const int q   = lane >> 4;
  const int l16 = lane & 15;
  const int srow = tid >> 2;       // staging row 0..63
  const int sseg = (tid & 3) * 8;  // 16B chunk within 32-elem row

  f32x4 acc[4][4];
#pragma unroll
  for (int i = 0; i < 4; ++i)
#pragma unroll
    for (int j = 0; j < 4; ++j)
      acc[i][j] = (f32x4){0.f, 0.f, 0.f, 0.f};

  const int kTiles = K >> 5;
  for (int kt = 0; kt < kTiles; ++kt) {
    const int kb = kt * 32;
    int ra = r0 + srow;      if (ra > M - 1) ra = M - 1;
    int rb = r0 + 64 + srow; if (rb > M - 1) rb = M - 1;
    const int4 va0 = *(const int4*)(A  + (size_t)ra * K + kb + sseg);
    const int4 va1 = *(const int4*)(A  + (size_t)rb * K + kb + sseg);
    const int4 vb0 = *(const int4*)(Bt + (size_t)(c0 + srow) * K + kb + sseg);
    const int4 vb1 = *(const int4*)(Bt + (size_t)(c0 + 64 + srow) * K + kb + sseg);
    *(int4*)(As + srow * 32 + sseg)        = va0;
    *(int4*)(As + (64 + srow) * 32 + sseg) = va1;
    *(int4*)(Bs + srow * 32 + sseg)        = vb0;
    *(int4*)(Bs + (64 + srow) * 32 + sseg) = vb1;
    __syncthreads();

    bf16x8 af[4], bfv[4];
#pragma unroll
    for (int i = 0; i < 4; ++i)
      af[i] = *(const bf16x8*)(As + (wr + i * 16 + l16) * 32 + q * 8);
#pragma unroll
    for (int j = 0; j < 4; ++j)
      bfv[j] = *(const bf16x8*)(Bs + (wc + j * 16 + l16) * 32 + q * 8);
#pragma unroll
    for (int i = 0; i < 4; ++i)
#pragma unroll
      for (int j = 0; j < 4; ++j)
        acc[i][j] = __builtin_amdgcn_mfma_f32_16x16x32_bf16(af[i], bfv[j], acc[i][j], 0, 0, 0);
    __syncthreads();
  }

  const bool f32out = final_out && (*flag == 0);
  // C/D layout: col=lane&15, row=(lane>>4)*4+reg  (m89-verified)
#pragma unroll
  for (int i = 0; i < 4; ++i) {
#pragma unroll
    for (int r = 0; r < 4; ++r) {
      int row = r0 + wr + i * 16 + q * 4 + r;
      if (row < M) {
#pragma unroll
        for (int j = 0; j < 4; ++j) {
          int col = c0 + wc + j * 16 + l16;
          float s = 1.0f / (1.0f + __expf(-acc[i][j][r]));
          if (f32out) ((float*)C)[(size_t)row * N + col] = s;
          else        ((bf16_t*)C)[(size_t)row * N + col] = (bf16_t)s;
        }
      }
    }
  }
}

// ---------------- host ----------------
extern "C" void kernel_launch(void* const* d_in, const int* in_sizes, int n_in,
                              void* d_out, int out_size, void* d_ws, size_t ws_size,
                              hipStream_t stream) {
  const void* x    = d_in[0];
  const void* W1   = d_in[1];
  const void* W2   = d_in[2];
  const int*  ei   = (const int*)d_in[3];
  const int*  fi   = (const int*)d_in[4];
  const void* vals = d_in[5];
  const int nnz = in_sizes[3];

  char* ws = (char*)d_ws;
  size_t off = 0;
  auto alloc = [&](size_t bytes) -> void* {
    void* p = ws + off;
    off = (off + bytes + 511) & ~((size_t)511);
    return p;
  };
  // pipeline (commuted): s1 = (B2 x)/deg_e ; h = sig(s1 W1) ; g = (B2^T h)/deg_f ; out = sig(g W2)
  bf16_t* s1g  = (bf16_t*)alloc((size_t)N_EDGES_C * CH * 2);  // s1 (60000 rows), later g (40000 rows)
  bf16_t* h    = (bf16_t*)alloc((size_t)N_EDGES_C * CH * 2);
  bf16_t* w1t  = (bf16_t*)alloc((size_t)CH * CH * 2);
  bf16_t* w2t  = (bf16_t*)alloc((size_t)CH * CH * 2);
  float* deg_e = (float*)alloc((size_t)N_EDGES_C * 4);  // --- zeroed block start ---
  float* deg_f = (float*)alloc((size_t)N_FACES_C * 4);
  int*   cnt_e = (int*)alloc((size_t)N_EDGES_C * 4);
  int*   cnt_f = (int*)alloc((size_t)N_FACES_C * 4);
  size_t zero_bytes = (size_t)((char*)cnt_f + (size_t)N_FACES_C * 4 - (char*)deg_e);
  int*   ptr_e = (int*)alloc((size_t)(N_EDGES_C + 1) * 4);
  int*   ptr_f = (int*)alloc((size_t)(N_FACES_C + 1) * 4);
  int*   cur_e = (int*)alloc((size_t)N_EDGES_C * 4);
  int*   cur_f = (int*)alloc((size_t)N_FACES_C * 4);
  int*   col_e = (int*)alloc((size_t)nnz * 4);
  float* val_e = (float*)alloc((size_t)nnz * 4);
  int*   col_f = (int*)alloc((size_t)nnz * 4);
  float* val_f = (float*)alloc((size_t)nnz * 4);
  int*   bsum  = (int*)alloc(64 * 4);
  int*   flag  = (int*)alloc(4);
  bf16_t* s1 = s1g;
  bf16_t* g  = s1g;

  detect_dtype<<<1, 64, 0, stream>>>((const unsigned int*)vals, flag);
  hipMemsetAsync(deg_e, 0, zero_bytes, stream);
  count_deg_kernel<<<(nnz + 255) / 256, 256, 0, stream>>>(ei, fi, vals, nnz,
                                                          deg_e, deg_f, cnt_e, cnt_f, flag);

  int nbE = (N_EDGES_C + 1023) / 1024, nbF = (N_FACES_C + 1023) / 1024;
  scan_part <<<nbE, 256, 0, stream>>>(cnt_e, N_EDGES_C, bsum);
  scan_bsums<<<1, 64, 0, stream>>>(bsum, nbE);
  scan_final<<<nbE, 256, 0, stream>>>(cnt_e, N_EDGES_C, bsum, ptr_e, cur_e);
  scan_part <<<nbF, 256, 0, stream>>>(cnt_f, N_FACES_C, bsum);
  scan_bsums<<<1, 64, 0, stream>>>(bsum, nbF);
  scan_final<<<nbF, 256, 0, stream>>>(cnt_f, N_FACES_C, bsum, ptr_f, cur_f);
  csr_fill<<<(nnz + 255) / 256, 256, 0, stream>>>(ei, fi, vals, nnz,
                                                  cur_e, col_e, val_e, cur_f, col_f, val_f, flag);

  transposeW<<<dim3(16, 16), dim3(32, 8), 0, stream>>>(W1, w1t, flag);
  transposeW<<<dim3(16, 16), dim3(32, 8), 0, stream>>>(W2, w2t, flag);

  // s1 = (B2 x)/deg_e   [60000 x 512]
  spmm_div<<<(N_EDGES_C + 3) / 4, 256, 0, stream>>>(ptr_e, col_e, val_e, x, deg_e, s1,
                                                    N_EDGES_C, N_FACES_C, nnz, flag, 0);
  // h = sigmoid(s1 @ W1)
  gemm_sig<<<dim3((N_EDGES_C + 127) / 128, CH / 128), 256, 0, stream>>>(s1, w1t, h,
                                                                        N_EDGES_C, CH, CH, flag, 0);
  // g = (B2^T h)/deg_f   [40000 x 512]
  spmm_div<<<(N_FACES_C + 3) / 4, 256, 0, stream>>>(ptr_f, col_f, val_f, h, deg_f, g,
                                                    N_FACES_C, N_EDGES_C, nnz, flag, 1);
  // out = sigmoid(g @ W2)  (dtype per flag)
  gemm_sig<<<dim3((N_FACES_C + 127) / 128, CH / 128), 256, 0, stream>>>(g, w2t, d_out,
                                                                        N_FACES_C, CH, CH, flag, 1);
}

// Round 4
// 341.640 us; speedup vs baseline: 1.0213x; 1.0213x over previous
//
#include <hip/hip_runtime.h>
#include <cstdint>

#define N_FACES_C 40000
#define N_EDGES_C 60000
#define CH        512

typedef __bf16 bf16_t;
typedef __bf16 bf16x8 __attribute__((ext_vector_type(8)));
typedef float  f32x4  __attribute__((ext_vector_type(4)));
static_assert(sizeof(bf16x8) == 16, "bf16x8 must be 16B");

// ---------------- runtime input-dtype detection ----------------
// vals is all-ones: first u32 word = 0x3F803F80 if bf16-packed, 0x3F800000 if f32.
__global__ void detect_dtype(const unsigned int* __restrict__ vals_bits, int* __restrict__ flag) {
  if (blockIdx.x == 0 && threadIdx.x == 0)
    *flag = (vals_bits[0] == 0x3F803F80u) ? 1 : 0;  // 1 = inputs are bf16
}

__device__ __forceinline__ float load_val(const void* vals, int i, bool isbf16) {
  return isbf16 ? (float)((const bf16_t*)vals)[i] : ((const float*)vals)[i];
}

// ---------------- degree + count (atomic histogram) ----------------
__global__ void count_deg_kernel(const int* __restrict__ ei, const int* __restrict__ fi,
                                 const void* __restrict__ vals, int nnz,
                                 float* __restrict__ deg_e, float* __restrict__ deg_f,
                                 int* __restrict__ cnt_e, int* __restrict__ cnt_f,
                                 const int* __restrict__ flag) {
  int i = blockIdx.x * 256 + threadIdx.x;
  if (i >= nnz) return;
  bool isb = (*flag != 0);
  float v = load_val(vals, i, isb);
  int e = ei[i], f = fi[i];
  atomicAdd(&deg_e[e], v);
  atomicAdd(&deg_f[f], v);
  atomicAdd(&cnt_e[e], 1);
  atomicAdd(&cnt_f[f], 1);
}

// ---------------- 3-phase exclusive scan (chunk = 1024/block) ----------------
__global__ void scan_part(const int* __restrict__ cnt, int n, int* __restrict__ bsum) {
  __shared__ int wsum[4];
  int b = blockIdx.x, t = threadIdx.x;
  int lane = t & 63, wave = t >> 6;
  int base = b * 1024 + t * 4;
  int s = 0;
#pragma unroll
  for (int k = 0; k < 4; ++k) {
    int idx = base + k;
    if (idx < n) s += cnt[idx];
  }
#pragma unroll
  for (int o = 32; o > 0; o >>= 1) s += __shfl_down(s, o);
  if (lane == 0) wsum[wave] = s;
  __syncthreads();
  if (t == 0) bsum[b] = wsum[0] + wsum[1] + wsum[2] + wsum[3];
}

__global__ void scan_bsums(int* bsum, int nb) {
  int lane = threadIdx.x;  // 64 threads, nb <= 64
  int orig = (lane < nb) ? bsum[lane] : 0;
  int v = orig;
#pragma unroll
  for (int o = 1; o < 64; o <<= 1) {
    int u = __shfl_up(v, o);
    if (lane >= o) v += u;
  }
  if (lane < nb) bsum[lane] = v - orig;  // exclusive
}

__global__ void scan_final(const int* __restrict__ cnt, int n, const int* __restrict__ bsum,
                           int* __restrict__ ptr, int* __restrict__ cur) {
  __shared__ int wsum[4];
  int b = blockIdx.x, t = threadIdx.x;
  int lane = t & 63, wave = t >> 6;
  int base = b * 1024 + t * 4;
  int c[4];
  int s = 0;
#pragma unroll
  for (int k = 0; k < 4; ++k) {
    int idx = base + k;
    c[k] = (idx < n) ? cnt[idx] : 0;
    s += c[k];
  }
  int v = s;
#pragma unroll
  for (int o = 1; o < 64; o <<= 1) {
    int u = __shfl_up(v, o);
    if (lane >= o) v += u;
  }
  if (lane == 63) wsum[wave] = v;
  __syncthreads();
  int woff = 0;
  for (int w = 0; w < wave; ++w) woff += wsum[w];
  int run = bsum[b] + woff + (v - s);
#pragma unroll
  for (int k = 0; k < 4; ++k) {
    int idx = base + k;
    if (idx < n) {
      ptr[idx] = run;
      cur[idx] = run;
      run += c[k];
      if (idx == n - 1) ptr[n] = run;
    }
  }
}

// ---------------- CSR fill (both directions in one pass) ----------------
__global__ void csr_fill(const int* __restrict__ ei, const int* __restrict__ fi,
                         const void* __restrict__ vals, int nnz,
                         int* __restrict__ cur_e, int* __restrict__ col_e, float* __restrict__ val_e,
                         int* __restrict__ cur_f, int* __restrict__ col_f, float* __restrict__ val_f,
                         const int* __restrict__ flag) {
  int i = blockIdx.x * 256 + threadIdx.x;
  if (i >= nnz) return;
  bool isb = (*flag != 0);
  int e = ei[i], f = fi[i];
  float v = load_val(vals, i, isb);
  int p = atomicAdd(&cur_e[e], 1);
  col_e[p] = f; val_e[p] = v;
  int q = atomicAdd(&cur_f[f], 1);
  col_f[q] = e; val_f[q] = v;
}

// ---------------- 512x512 transpose (W -> W^T, bf16 out, dtype-flag in) ----------------
__global__ void transposeW(const void* __restrict__ W, bf16_t* __restrict__ Wt,
                           const int* __restrict__ flag) {
  __shared__ bf16_t tile[32][33];
  bool isb = (*flag != 0);
  int bx = blockIdx.x * 32, by = blockIdx.y * 32;
  int tx = threadIdx.x, ty = threadIdx.y;  // (32, 8)
#pragma unroll
  for (int r = 0; r < 32; r += 8) {
    size_t idx = (size_t)(by + ty + r) * CH + bx + tx;
    tile[ty + r][tx] = isb ? ((const bf16_t*)W)[idx] : (bf16_t)((const float*)W)[idx];
  }
  __syncthreads();
#pragma unroll
  for (int r = 0; r < 32; r += 8)
    Wt[(size_t)(bx + ty + r) * CH + by + tx] = tile[tx][ty + r];
}

// ---------------- CSR-gather SpMM + deg-divide (one wave per row), bf16 out ----------------
// X dtype: bf16 if (force_bf16 || *flag), else f32.
__global__ void spmm_div(const int* __restrict__ ptr, const int* __restrict__ cols,
                         const float* __restrict__ vals, const void* __restrict__ X,
                         const float* __restrict__ deg, bf16_t* __restrict__ Y,
                         int nRows, int nCols, int nnz,
                         const int* __restrict__ flag, int force_bf16) {
  int row = blockIdx.x * 4 + (threadIdx.x >> 6);
  if (row >= nRows) return;
  bool xb = force_bf16 || (*flag != 0);
  int lane = threadIdx.x & 63;
  int beg = ptr[row], end = ptr[row + 1];
  if (beg < 0) beg = 0;
  if (end > nnz) end = nnz;
  float acc[8];
#pragma unroll
  for (int t = 0; t < 8; ++t) acc[t] = 0.f;
  const int lofs = lane * 8;
  if (xb) {
    const bf16_t* Xb = (const bf16_t*)X;
    for (int p = beg; p < end; ++p) {
      int c = cols[p];
      if ((unsigned)c >= (unsigned)nCols) c = 0;  // insurance vs wild index
      float v = vals[p];
      bf16x8 xv = *(const bf16x8*)(Xb + (size_t)c * CH + lofs);
#pragma unroll
      for (int t = 0; t < 8; ++t) acc[t] += v * (float)xv[t];
    }
  } else {
    const float* Xf = (const float*)X;
    for (int p = beg; p < end; ++p) {
      int c = cols[p];
      if ((unsigned)c >= (unsigned)nCols) c = 0;
      float v = vals[p];
      const float* src = Xf + (size_t)c * CH + lofs;
      float4 a = *(const float4*)src;
      float4 b = *(const float4*)(src + 4);
      acc[0] += v * a.x; acc[1] += v * a.y; acc[2] += v * a.z; acc[3] += v * a.w;
      acc[4] += v * b.x; acc[5] += v * b.y; acc[6] += v * b.z; acc[7] += v * b.w;
    }
  }
  float d = deg[row];
  float invd = (d != 0.f) ? (1.0f / d) : 0.f;
  bf16x8 o;
#pragma unroll
  for (int t = 0; t < 8; ++t) o[t] = (bf16_t)(acc[t] * invd);
  *(bf16x8*)(Y + (size_t)row * CH + lofs) = o;
}

// ---------------- bf16 GEMM + sigmoid epilogue: C = sigmoid(A[M,K] * B), Bt = B^T ----------------
// m97-style async staging (global_load_lds width=16) + XOR k-seg swizzle vs bank conflicts.
// LDS layout: slot(row, s) 16B, addr = row*64B + s*16B; holds global k-seg (s ^ ((row>>1)&3)).
// Grid: (N/128, M/128) — x = column block, fastest-varying, so the 4 col-blocks
// sharing an A row-tile dispatch adjacently (L2/L3 A-reuse).
// Output: bf16 unless (final_out && *flag==0) -> f32.
__global__ __launch_bounds__(256)
void gemm_sig(const bf16_t* __restrict__ A, const bf16_t* __restrict__ Bt,
              void* __restrict__ C, int M, int N, int K,
              const int* __restrict__ flag, int final_out) {
  __shared__ __align__(16) bf16_t As[128 * 32];  // [row][k-slot]
  __shared__ __align__(16) bf16_t Bs[128 * 32];  // [n][k-slot]
  const int tid  = threadIdx.x;
  const int lane = tid & 63;
  const int wave = tid >> 6;
  const int r0 = blockIdx.y * 128;
  const int c0 = blockIdx.x * 128;
  const int wr = (wave >> 1) * 64;
  const int wc = (wave & 1) * 64;
  const int q   = lane >> 4;
  const int l16 = lane & 15;
  // staging: wave w covers LDS rows 16w..16w+15 (and +64); lane -> (row, seg_slot)
  const int srow = wave * 16 + (lane >> 2);       // LDS-local row, chunk 0
  const int sw   = (srow >> 1) & 3;               // swizzle bits (identical for row+64)
  const int gofs = ((lane & 3) ^ sw) * 8;         // global k-offset this lane fetches
  // fragment reads: row = base + l16 -> swizzle bits depend only on l16
  const int swr  = (l16 >> 1) & 3;
  const int rofs = (q ^ swr) * 8;                 // k-slot offset to read for seg q

  f32x4 acc[4][4];
#pragma unroll
  for (int i = 0; i < 4; ++i)
#pragma unroll
    for (int j = 0; j < 4; ++j)
      acc[i][j] = (f32x4){0.f, 0.f, 0.f, 0.f};

  const int kTiles = K >> 5;
  for (int kt = 0; kt < kTiles; ++kt) {
    const int kb = kt * 32;
    int ra = r0 + srow;      if (ra > M - 1) ra = M - 1;
    int rb = r0 + 64 + srow; if (rb > M - 1) rb = M - 1;
    const bf16_t* ga0 = A  + (size_t)ra * K + kb + gofs;
    const bf16_t* ga1 = A  + (size_t)rb * K + kb + gofs;
    const bf16_t* gb0 = Bt + (size_t)(c0 + srow) * K + kb + gofs;
    const bf16_t* gb1 = Bt + (size_t)(c0 + 64 + srow) * K + kb + gofs;
    // async DMA global->LDS, 16B/lane; LDS dest = wave-uniform base + lane*16
    __builtin_amdgcn_global_load_lds((const __attribute__((address_space(1))) void*)ga0,
                                     (__attribute__((address_space(3))) void*)(As + wave * 512), 16, 0, 0);
    __builtin_amdgcn_global_load_lds((const __attribute__((address_space(1))) void*)ga1,
                                     (__attribute__((address_space(3))) void*)(As + 2048 + wave * 512), 16, 0, 0);
    __builtin_amdgcn_global_load_lds((const __attribute__((address_space(1))) void*)gb0,
                                     (__attribute__((address_space(3))) void*)(Bs + wave * 512), 16, 0, 0);
    __builtin_amdgcn_global_load_lds((const __attribute__((address_space(1))) void*)gb1,
                                     (__attribute__((address_space(3))) void*)(Bs + 2048 + wave * 512), 16, 0, 0);
    __syncthreads();

    bf16x8 af[4], bfv[4];
#pragma unroll
    for (int i = 0; i < 4; ++i)
      af[i] = *(const bf16x8*)(As + (wr + i * 16 + l16) * 32 + rofs);
#pragma unroll
    for (int j = 0; j < 4; ++j)
      bfv[j] = *(const bf16x8*)(Bs + (wc + j * 16 + l16) * 32 + rofs);
#pragma unroll
    for (int i = 0; i < 4; ++i)
#pragma unroll
      for (int j = 0; j < 4; ++j)
        acc[i][j] = __builtin_amdgcn_mfma_f32_16x16x32_bf16(af[i], bfv[j], acc[i][j], 0, 0, 0);
    __syncthreads();
  }

  const bool f32out = final_out && (*flag == 0);
  // C/D layout: col=lane&15, row=(lane>>4)*4+reg  (m89-verified)
#pragma unroll
  for (int i = 0; i < 4; ++i) {
#pragma unroll
    for (int r = 0; r < 4; ++r) {
      int row = r0 + wr + i * 16 + q * 4 + r;
      if (row < M) {
#pragma unroll
        for (int j = 0; j < 4; ++j) {
          int col = c0 + wc + j * 16 + l16;
          float s = 1.0f / (1.0f + __expf(-acc[i][j][r]));
          if (f32out) ((float*)C)[(size_t)row * N + col] = s;
          else        ((bf16_t*)C)[(size_t)row * N + col] = (bf16_t)s;
        }
      }
    }
  }
}

// ---------------- host ----------------
extern "C" void kernel_launch(void* const* d_in, const int* in_sizes, int n_in,
                              void* d_out, int out_size, void* d_ws, size_t ws_size,
                              hipStream_t stream) {
  const void* x    = d_in[0];
  const void* W1   = d_in[1];
  const void* W2   = d_in[2];
  const int*  ei   = (const int*)d_in[3];
  const int*  fi   = (const int*)d_in[4];
  const void* vals = d_in[5];
  const int nnz = in_sizes[3];

  char* ws = (char*)d_ws;
  size_t off = 0;
  auto alloc = [&](size_t bytes) -> void* {
    void* p = ws + off;
    off = (off + bytes + 511) & ~((size_t)511);
    return p;
  };
  // pipeline (commuted): s1 = (B2 x)/deg_e ; h = sig(s1 W1) ; g = (B2^T h)/deg_f ; out = sig(g W2)
  bf16_t* s1g  = (bf16_t*)alloc((size_t)N_EDGES_C * CH * 2);  // s1 (60000 rows), later g (40000 rows)
  bf16_t* h    = (bf16_t*)alloc((size_t)N_EDGES_C * CH * 2);
  bf16_t* w1t  = (bf16_t*)alloc((size_t)CH * CH * 2);
  bf16_t* w2t  = (bf16_t*)alloc((size_t)CH * CH * 2);
  float* deg_e = (float*)alloc((size_t)N_EDGES_C * 4);  // --- zeroed block start ---
  float* deg_f = (float*)alloc((size_t)N_FACES_C * 4);
  int*   cnt_e = (int*)alloc((size_t)N_EDGES_C * 4);
  int*   cnt_f = (int*)alloc((size_t)N_FACES_C * 4);
  size_t zero_bytes = (size_t)((char*)cnt_f + (size_t)N_FACES_C * 4 - (char*)deg_e);
  int*   ptr_e = (int*)alloc((size_t)(N_EDGES_C + 1) * 4);
  int*   ptr_f = (int*)alloc((size_t)(N_FACES_C + 1) * 4);
  int*   cur_e = (int*)alloc((size_t)N_EDGES_C * 4);
  int*   cur_f = (int*)alloc((size_t)N_FACES_C * 4);
  int*   col_e = (int*)alloc((size_t)nnz * 4);
  float* val_e = (float*)alloc((size_t)nnz * 4);
  int*   col_f = (int*)alloc((size_t)nnz * 4);
  float* val_f = (float*)alloc((size_t)nnz * 4);
  int*   bsum  = (int*)alloc(64 * 4);
  int*   flag  = (int*)alloc(4);
  bf16_t* s1 = s1g;
  bf16_t* g  = s1g;

  detect_dtype<<<1, 64, 0, stream>>>((const unsigned int*)vals, flag);
  hipMemsetAsync(deg_e, 0, zero_bytes, stream);
  count_deg_kernel<<<(nnz + 255) / 256, 256, 0, stream>>>(ei, fi, vals, nnz,
                                                          deg_e, deg_f, cnt_e, cnt_f, flag);

  int nbE = (N_EDGES_C + 1023) / 1024, nbF = (N_FACES_C + 1023) / 1024;
  scan_part <<<nbE, 256, 0, stream>>>(cnt_e, N_EDGES_C, bsum);
  scan_bsums<<<1, 64, 0, stream>>>(bsum, nbE);
  scan_final<<<nbE, 256, 0, stream>>>(cnt_e, N_EDGES_C, bsum, ptr_e, cur_e);
  scan_part <<<nbF, 256, 0, stream>>>(cnt_f, N_FACES_C, bsum);
  scan_bsums<<<1, 64, 0, stream>>>(bsum, nbF);
  scan_final<<<nbF, 256, 0, stream>>>(cnt_f, N_FACES_C, bsum, ptr_f, cur_f);
  csr_fill<<<(nnz + 255) / 256, 256, 0, stream>>>(ei, fi, vals, nnz,
                                                  cur_e, col_e, val_e, cur_f, col_f, val_f, flag);

  transposeW<<<dim3(16, 16), dim3(32, 8), 0, stream>>>(W1, w1t, flag);
  transposeW<<<dim3(16, 16), dim3(32, 8), 0, stream>>>(W2, w2t, flag);

  // s1 = (B2 x)/deg_e   [60000 x 512]
  spmm_div<<<(N_EDGES_C + 3) / 4, 256, 0, stream>>>(ptr_e, col_e, val_e, x, deg_e, s1,
                                                    N_EDGES_C, N_FACES_C, nnz, flag, 0);
  // h = sigmoid(s1 @ W1)
  gemm_sig<<<dim3(CH / 128, (N_EDGES_C + 127) / 128), 256, 0, stream>>>(s1, w1t, h,
                                                                        N_EDGES_C, CH, CH, flag, 0);
  // g = (B2^T h)/deg_f   [40000 x 512]
  spmm_div<<<(N_FACES_C + 3) / 4, 256, 0, stream>>>(ptr_f, col_f, val_f, h, deg_f, g,
                                                    N_FACES_C, N_EDGES_C, nnz, flag, 1);
  // out = sigmoid(g @ W2)  (dtype per flag)
  gemm_sig<<<dim3(CH / 128, (N_FACES_C + 127) / 128), 256, 0, stream>>>(g, w2t, d_out,
                                                                        N_FACES_C, CH, CH, flag, 1);
}

// Round 5
// 317.347 us; speedup vs baseline: 1.0995x; 1.0766x over previous
//
#include <hip/hip_runtime.h>
#include <cstdint>

#define N_FACES_C 40000
#define N_EDGES_C 60000
#define CH        512

typedef __bf16 bf16_t;
typedef __bf16 bf16x8 __attribute__((ext_vector_type(8)));
typedef float  f32x4  __attribute__((ext_vector_type(4)));
static_assert(sizeof(bf16x8) == 16, "bf16x8 must be 16B");

// ---------------- runtime input-dtype detection ----------------
__global__ void detect_dtype(const unsigned int* __restrict__ vals_bits, int* __restrict__ flag) {
  if (blockIdx.x == 0 && threadIdx.x == 0)
    *flag = (vals_bits[0] == 0x3F803F80u) ? 1 : 0;  // 1 = inputs are bf16
}

__device__ __forceinline__ float load_val(const void* vals, int i, bool isbf16) {
  return isbf16 ? (float)((const bf16_t*)vals)[i] : ((const float*)vals)[i];
}

__device__ __forceinline__ float fast_sigmoid(float z) {
  // v_exp_f32 + v_rcp_f32: ~1ulp each, error ~1e-7 abs on (0,1) — far below bf16 ulp
  float e = __builtin_amdgcn_exp2f(z * -1.44269504f);
  return __builtin_amdgcn_rcpf(1.0f + e);
}

// ---------------- degree + count (atomic histogram) ----------------
__global__ void count_deg_kernel(const int* __restrict__ ei, const int* __restrict__ fi,
                                 const void* __restrict__ vals, int nnz,
                                 float* __restrict__ deg_e, float* __restrict__ deg_f,
                                 int* __restrict__ cnt_e, int* __restrict__ cnt_f,
                                 const int* __restrict__ flag) {
  int i = blockIdx.x * 256 + threadIdx.x;
  if (i >= nnz) return;
  bool isb = (*flag != 0);
  float v = load_val(vals, i, isb);
  int e = ei[i], f = fi[i];
  atomicAdd(&deg_e[e], v);
  atomicAdd(&deg_f[f], v);
  atomicAdd(&cnt_e[e], 1);
  atomicAdd(&cnt_f[f], 1);
}

// ---------------- batched 3-phase exclusive scan (e and f in one grid) ----------------
__global__ void scan_part2(const int* __restrict__ cntE, int nE, int* __restrict__ bsumE,
                           const int* __restrict__ cntF, int nF, int* __restrict__ bsumF,
                           int nbE) {
  __shared__ int wsum[4];
  int bx = blockIdx.x;
  const int* cnt; int n; int* bsum; int b;
  if (bx < nbE) { cnt = cntE; n = nE; bsum = bsumE; b = bx; }
  else          { cnt = cntF; n = nF; bsum = bsumF; b = bx - nbE; }
  int t = threadIdx.x;
  int lane = t & 63, wave = t >> 6;
  int base = b * 1024 + t * 4;
  int s = 0;
#pragma unroll
  for (int k = 0; k < 4; ++k) {
    int idx = base + k;
    if (idx < n) s += cnt[idx];
  }
#pragma unroll
  for (int o = 32; o > 0; o >>= 1) s += __shfl_down(s, o);
  if (lane == 0) wsum[wave] = s;
  __syncthreads();
  if (t == 0) bsum[b] = wsum[0] + wsum[1] + wsum[2] + wsum[3];
}

__global__ void scan_bsums2(int* __restrict__ bsumE, int nbE, int* __restrict__ bsumF, int nbF) {
  int wave = threadIdx.x >> 6;          // 0 -> e, 1 -> f
  int lane = threadIdx.x & 63;
  int* bsum = wave ? bsumF : bsumE;
  int nb    = wave ? nbF   : nbE;
  int orig = (lane < nb) ? bsum[lane] : 0;
  int v = orig;
#pragma unroll
  for (int o = 1; o < 64; o <<= 1) {
    int u = __shfl_up(v, o);
    if (lane >= o) v += u;
  }
  if (lane < nb) bsum[lane] = v - orig;  // exclusive
}

__global__ void scan_final2(const int* __restrict__ cntE, int nE, const int* __restrict__ bsumE,
                            int* __restrict__ ptrE, int* __restrict__ curE,
                            const int* __restrict__ cntF, int nF, const int* __restrict__ bsumF,
                            int* __restrict__ ptrF, int* __restrict__ curF, int nbE) {
  __shared__ int wsum[4];
  int bx = blockIdx.x;
  const int* cnt; int n; const int* bsum; int* ptr; int* cur; int b;
  if (bx < nbE) { cnt = cntE; n = nE; bsum = bsumE; ptr = ptrE; cur = curE; b = bx; }
  else          { cnt = cntF; n = nF; bsum = bsumF; ptr = ptrF; cur = curF; b = bx - nbE; }
  int t = threadIdx.x;
  int lane = t & 63, wave = t >> 6;
  int base = b * 1024 + t * 4;
  int c[4];
  int s = 0;
#pragma unroll
  for (int k = 0; k < 4; ++k) {
    int idx = base + k;
    c[k] = (idx < n) ? cnt[idx] : 0;
    s += c[k];
  }
  int v = s;
#pragma unroll
  for (int o = 1; o < 64; o <<= 1) {
    int u = __shfl_up(v, o);
    if (lane >= o) v += u;
  }
  if (lane == 63) wsum[wave] = v;
  __syncthreads();
  int woff = 0;
  for (int w = 0; w < wave; ++w) woff += wsum[w];
  int run = bsum[b] + woff + (v - s);
#pragma unroll
  for (int k = 0; k < 4; ++k) {
    int idx = base + k;
    if (idx < n) {
      ptr[idx] = run;
      cur[idx] = run;
      run += c[k];
      if (idx == n - 1) ptr[n] = run;
    }
  }
}

// ---------------- CSR fill (both directions in one pass) ----------------
__global__ void csr_fill(const int* __restrict__ ei, const int* __restrict__ fi,
                         const void* __restrict__ vals, int nnz,
                         int* __restrict__ cur_e, int* __restrict__ col_e, float* __restrict__ val_e,
                         int* __restrict__ cur_f, int* __restrict__ col_f, float* __restrict__ val_f,
                         const int* __restrict__ flag) {
  int i = blockIdx.x * 256 + threadIdx.x;
  if (i >= nnz) return;
  bool isb = (*flag != 0);
  int e = ei[i], f = fi[i];
  float v = load_val(vals, i, isb);
  int p = atomicAdd(&cur_e[e], 1);
  col_e[p] = f; val_e[p] = v;
  int q = atomicAdd(&cur_f[f], 1);
  col_f[q] = e; val_f[q] = v;
}

// ---------------- 512x512 transpose (both W1 and W2 in one grid via z) ----------------
__global__ void transposeW2(const void* __restrict__ W1, bf16_t* __restrict__ W1t,
                            const void* __restrict__ W2, bf16_t* __restrict__ W2t,
                            const int* __restrict__ flag) {
  __shared__ bf16_t tile[32][33];
  bool isb = (*flag != 0);
  const void* W = blockIdx.z ? W2 : W1;
  bf16_t*    Wt = blockIdx.z ? W2t : W1t;
  int bx = blockIdx.x * 32, by = blockIdx.y * 32;
  int tx = threadIdx.x, ty = threadIdx.y;  // (32, 8)
#pragma unroll
  for (int r = 0; r < 32; r += 8) {
    size_t idx = (size_t)(by + ty + r) * CH + bx + tx;
    tile[ty + r][tx] = isb ? ((const bf16_t*)W)[idx] : (bf16_t)((const float*)W)[idx];
  }
  __syncthreads();
#pragma unroll
  for (int r = 0; r < 32; r += 8)
    Wt[(size_t)(bx + ty + r) * CH + by + tx] = tile[tx][ty + r];
}

// ---------------- CSR-gather SpMM + deg-divide (one wave per row), bf16 out ----------------
__global__ void spmm_div(const int* __restrict__ ptr, const int* __restrict__ cols,
                         const float* __restrict__ vals, const void* __restrict__ X,
                         const float* __restrict__ deg, bf16_t* __restrict__ Y,
                         int nRows, int nCols, int nnz,
                         const int* __restrict__ flag, int force_bf16) {
  int row = blockIdx.x * 4 + (threadIdx.x >> 6);
  if (row >= nRows) return;
  bool xb = force_bf16 || (*flag != 0);
  int lane = threadIdx.x & 63;
  int beg = ptr[row], end = ptr[row + 1];
  if (beg < 0) beg = 0;
  if (end > nnz) end = nnz;
  float acc[8];
#pragma unroll
  for (int t = 0; t < 8; ++t) acc[t] = 0.f;
  const int lofs = lane * 8;
  if (xb) {
    const bf16_t* Xb = (const bf16_t*)X;
    for (int p = beg; p < end; ++p) {
      int c = cols[p];
      if ((unsigned)c >= (unsigned)nCols) c = 0;
      float v = vals[p];
      bf16x8 xv = *(const bf16x8*)(Xb + (size_t)c * CH + lofs);
#pragma unroll
      for (int t = 0; t < 8; ++t) acc[t] += v * (float)xv[t];
    }
  } else {
    const float* Xf = (const float*)X;
    for (int p = beg; p < end; ++p) {
      int c = cols[p];
      if ((unsigned)c >= (unsigned)nCols) c = 0;
      float v = vals[p];
      const float* src = Xf + (size_t)c * CH + lofs;
      float4 a = *(const float4*)src;
      float4 b = *(const float4*)(src + 4);
      acc[0] += v * a.x; acc[1] += v * a.y; acc[2] += v * a.z; acc[3] += v * a.w;
      acc[4] += v * b.x; acc[5] += v * b.y; acc[6] += v * b.z; acc[7] += v * b.w;
    }
  }
  float d = deg[row];
  float invd = (d != 0.f) ? (1.0f / d) : 0.f;
  bf16x8 o;
#pragma unroll
  for (int t = 0; t < 8; ++t) o[t] = (bf16_t)(acc[t] * invd);
  *(bf16x8*)(Y + (size_t)row * CH + lofs) = o;
}

// ---------------- bf16 GEMM + sigmoid epilogue, BK=64 ----------------
// C = sigmoid(A[M,K] * B), Bt = B^T [N,K].
// LDS row = 64 bf16 = 128 B = 8 x 16B segs; slot(row, s) holds global seg s ^ (row & 7).
// Staging: global_load_lds width=16, wave-uniform base + lane*16 (8 rows/wave/issue).
// 16 barriers/block instead of 32 (K/64 = 8 iters x 2).
__global__ __launch_bounds__(256)
void gemm_sig(const bf16_t* __restrict__ A, const bf16_t* __restrict__ Bt,
              void* __restrict__ C, int M, int N, int K,
              const int* __restrict__ flag, int final_out) {
  __shared__ __align__(16) bf16_t As[128 * 64];  // 16 KB
  __shared__ __align__(16) bf16_t Bs[128 * 64];  // 16 KB
  const int tid  = threadIdx.x;
  const int lane = tid & 63;
  const int wave = tid >> 6;
  const int r0 = blockIdx.y * 128;
  const int c0 = blockIdx.x * 128;
  const int wr = (wave >> 1) * 64;
  const int wc = (wave & 1) * 64;
  const int q   = lane >> 4;
  const int l16 = lane & 15;
  // staging: per issue i (0..3), this lane covers LDS-local row i*32 + wave*8 + (lane>>3),
  // seg slot lane&7; fetches global seg (slot ^ (row&7)).
  const int srow_base = wave * 8 + (lane >> 3);
  const int sslot = lane & 7;

  f32x4 acc[4][4];
#pragma unroll
  for (int i = 0; i < 4; ++i)
#pragma unroll
    for (int j = 0; j < 4; ++j)
      acc[i][j] = (f32x4){0.f, 0.f, 0.f, 0.f};

  const int kTiles = K >> 6;  // 8
  for (int kt = 0; kt < kTiles; ++kt) {
    const int kb = kt * 64;
#pragma unroll
    for (int i = 0; i < 4; ++i) {
      const int lr = i * 32 + srow_base;                // 0..127
      const int gofs = (sslot ^ (lr & 7)) * 8;          // swizzled global k-offset
      int ra = r0 + lr; if (ra > M - 1) ra = M - 1;
      const bf16_t* ga = A  + (size_t)ra * K + kb + gofs;
      const bf16_t* gb = Bt + (size_t)(c0 + lr) * K + kb + gofs;
      __builtin_amdgcn_global_load_lds((const __attribute__((address_space(1))) void*)ga,
                                       (__attribute__((address_space(3))) void*)(As + (i * 32 + wave * 8) * 64), 16, 0, 0);
      __builtin_amdgcn_global_load_lds((const __attribute__((address_space(1))) void*)gb,
                                       (__attribute__((address_space(3))) void*)(Bs + (i * 32 + wave * 8) * 64), 16, 0, 0);
    }
    __syncthreads();

#pragma unroll
    for (int kk = 0; kk < 2; ++kk) {
      // fragment rows are base + l16 with base % 8 == 0, so row&7 == l16&7
      const int slot = (kk * 4 + q) ^ (l16 & 7);
      const int ro = slot * 8;
      bf16x8 af[4], bfv[4];
#pragma unroll
      for (int i = 0; i < 4; ++i)
        af[i] = *(const bf16x8*)(As + (wr + i * 16 + l16) * 64 + ro);
#pragma unroll
      for (int j = 0; j < 4; ++j)
        bfv[j] = *(const bf16x8*)(Bs + (wc + j * 16 + l16) * 64 + ro);
#pragma unroll
      for (int i = 0; i < 4; ++i)
#pragma unroll
        for (int j = 0; j < 4; ++j)
          acc[i][j] = __builtin_amdgcn_mfma_f32_16x16x32_bf16(af[i], bfv[j], acc[i][j], 0, 0, 0);
    }
    __syncthreads();
  }

  const bool f32out = final_out && (*flag == 0);
  // C/D layout: col=lane&15, row=(lane>>4)*4+reg  (m89-verified)
#pragma unroll
  for (int i = 0; i < 4; ++i) {
#pragma unroll
    for (int r = 0; r < 4; ++r) {
      int row = r0 + wr + i * 16 + q * 4 + r;
      if (row < M) {
#pragma unroll
        for (int j = 0; j < 4; ++j) {
          int col = c0 + wc + j * 16 + l16;
          float s = fast_sigmoid(acc[i][j][r]);
          if (f32out) ((float*)C)[(size_t)row * N + col] = s;
          else        ((bf16_t*)C)[(size_t)row * N + col] = (bf16_t)s;
        }
      }
    }
  }
}

// ---------------- host ----------------
extern "C" void kernel_launch(void* const* d_in, const int* in_sizes, int n_in,
                              void* d_out, int out_size, void* d_ws, size_t ws_size,
                              hipStream_t stream) {
  const void* x    = d_in[0];
  const void* W1   = d_in[1];
  const void* W2   = d_in[2];
  const int*  ei   = (const int*)d_in[3];
  const int*  fi   = (const int*)d_in[4];
  const void* vals = d_in[5];
  const int nnz = in_sizes[3];

  char* ws = (char*)d_ws;
  size_t off = 0;
  auto alloc = [&](size_t bytes) -> void* {
    void* p = ws + off;
    off = (off + bytes + 511) & ~((size_t)511);
    return p;
  };
  // pipeline (commuted): s1 = (B2 x)/deg_e ; h = sig(s1 W1) ; g = (B2^T h)/deg_f ; out = sig(g W2)
  bf16_t* s1g  = (bf16_t*)alloc((size_t)N_EDGES_C * CH * 2);  // s1 (60000 rows), later g (40000 rows)
  bf16_t* h    = (bf16_t*)alloc((size_t)N_EDGES_C * CH * 2);
  bf16_t* w1t  = (bf16_t*)alloc((size_t)CH * CH * 2);
  bf16_t* w2t  = (bf16_t*)alloc((size_t)CH * CH * 2);
  float* deg_e = (float*)alloc((size_t)N_EDGES_C * 4);  // --- zeroed block start ---
  float* deg_f = (float*)alloc((size_t)N_FACES_C * 4);
  int*   cnt_e = (int*)alloc((size_t)N_EDGES_C * 4);
  int*   cnt_f = (int*)alloc((size_t)N_FACES_C * 4);
  size_t zero_bytes = (size_t)((char*)cnt_f + (size_t)N_FACES_C * 4 - (char*)deg_e);
  int*   ptr_e = (int*)alloc((size_t)(N_EDGES_C + 1) * 4);
  int*   ptr_f = (int*)alloc((size_t)(N_FACES_C + 1) * 4);
  int*   cur_e = (int*)alloc((size_t)N_EDGES_C * 4);
  int*   cur_f = (int*)alloc((size_t)N_FACES_C * 4);
  int*   col_e = (int*)alloc((size_t)nnz * 4);
  float* val_e = (float*)alloc((size_t)nnz * 4);
  int*   col_f = (int*)alloc((size_t)nnz * 4);
  float* val_f = (float*)alloc((size_t)nnz * 4);
  int*   bsumE = (int*)alloc(64 * 4);
  int*   bsumF = (int*)alloc(64 * 4);
  int*   flag  = (int*)alloc(4);
  bf16_t* s1 = s1g;
  bf16_t* g  = s1g;

  detect_dtype<<<1, 64, 0, stream>>>((const unsigned int*)vals, flag);
  hipMemsetAsync(deg_e, 0, zero_bytes, stream);
  count_deg_kernel<<<(nnz + 255) / 256, 256, 0, stream>>>(ei, fi, vals, nnz,
                                                          deg_e, deg_f, cnt_e, cnt_f, flag);

  int nbE = (N_EDGES_C + 1023) / 1024, nbF = (N_FACES_C + 1023) / 1024;
  scan_part2 <<<nbE + nbF, 256, 0, stream>>>(cnt_e, N_EDGES_C, bsumE, cnt_f, N_FACES_C, bsumF, nbE);
  scan_bsums2<<<1, 128, 0, stream>>>(bsumE, nbE, bsumF, nbF);
  scan_final2<<<nbE + nbF, 256, 0, stream>>>(cnt_e, N_EDGES_C, bsumE, ptr_e, cur_e,
                                             cnt_f, N_FACES_C, bsumF, ptr_f, cur_f, nbE);
  csr_fill<<<(nnz + 255) / 256, 256, 0, stream>>>(ei, fi, vals, nnz,
                                                  cur_e, col_e, val_e, cur_f, col_f, val_f, flag);

  transposeW2<<<dim3(16, 16, 2), dim3(32, 8), 0, stream>>>(W1, w1t, W2, w2t, flag);

  // s1 = (B2 x)/deg_e   [60000 x 512]
  spmm_div<<<(N_EDGES_C + 3) / 4, 256, 0, stream>>>(ptr_e, col_e, val_e, x, deg_e, s1,
                                                    N_EDGES_C, N_FACES_C, nnz, flag, 0);
  // h = sigmoid(s1 @ W1)
  gemm_sig<<<dim3(CH / 128, (N_EDGES_C + 127) / 128), 256, 0, stream>>>(s1, w1t, h,
                                                                        N_EDGES_C, CH, CH, flag, 0);
  // g = (B2^T h)/deg_f   [40000 x 512]
  spmm_div<<<(N_FACES_C + 3) / 4, 256, 0, stream>>>(ptr_f, col_f, val_f, h, deg_f, g,
                                                    N_FACES_C, N_EDGES_C, nnz, flag, 1);
  // out = sigmoid(g @ W2)  (dtype per flag)
  gemm_sig<<<dim3(CH / 128, (N_FACES_C + 127) / 128), 256, 0, stream>>>(g, w2t, d_out,
                                                                        N_FACES_C, CH, CH, flag, 1);
}